// Round 2
// baseline (337.679 us; speedup 1.0000x reference)
//
#include <hip/hip_runtime.h>

// B=16, V=20000, D=H=256. Output fp32 [16][20000].
// prep:  repack Wa/W1b to MFMA B-frag bf16 + patient path -> EpT[h][b]=exp2(C*ph)
// mega:  1250 blocks x 1 wave; per wave: GEMM1(bf16 MFMA)+LN (in-register) ->
//        wave-local LDS transpose -> GEMM2 -> fused tanh contraction -> scores
// final: stats reduce + LN over V, elementwise out.
// tanh(z) = 1 - 2/(1+e^{2z}); constants cancel under final LN (shift-invariant):
// out = -2*(S-mean_S)*rsqrt(4*var_S+eps)*g_pred + b_pred, S = sum_h W2/(1+e^{2z}).

typedef unsigned short ushort_t;
typedef __attribute__((ext_vector_type(8))) short short8;
typedef __attribute__((ext_vector_type(4))) float floatx4;

#define C2F 2.8853900817779268f  // 2*log2(e)
#define V_N 20000
#define NBLK 1250                // V_N / 16

__device__ __forceinline__ ushort_t f2bf(float f) {
    unsigned int u = __builtin_bit_cast(unsigned int, f);
    u += 0x7FFFu + ((u >> 16) & 1u);   // RNE
    return (ushort_t)(u >> 16);
}
__device__ __forceinline__ float exp2_fast(float x) { return __builtin_amdgcn_exp2f(x); }
__device__ __forceinline__ float rcp_fast(float x)  { return __builtin_amdgcn_rcpf(x); }

// ---------------------------------------------------------------------------
// prep: blocks 0..63 repack Wa / W1[D:] into B-frag order (validated in R1):
//   elem ((s*16+T)*64+l)*8+j = src[(s*32+(l>>4)*8+j)*256 + T*16+(l&15)]
// blocks 64..79: patient path, one block per b: LN(pe@Wp+bp) @ W1[:D] -> EpT
// ---------------------------------------------------------------------------
__global__ __launch_bounds__(256) void prep_kernel(
    const float* __restrict__ patient_emb, const float* __restrict__ Wp,
    const float* __restrict__ bp, const float* __restrict__ gp,
    const float* __restrict__ betap, const float* __restrict__ Wa,
    const float* __restrict__ W1, ushort_t* __restrict__ pWa,
    ushort_t* __restrict__ pW1b, float* __restrict__ EpT)
{
    const int blk = blockIdx.x, tid = threadIdx.x;
    __shared__ float peL[256], xb[256], redw[8], stat[2];

    if (blk < 64) {
        int slot = blk * 256 + tid;          // 16384 slots = 2 matrices * 8192
        int matrix = slot >> 13;
        int rest = slot & 8191;
        int s = rest >> 10, T = (rest >> 6) & 15, l = rest & 63;
        const float* src = matrix ? (W1 + 256 * 256) : Wa;
        ushort_t* dst = matrix ? pW1b : pWa;
        int kbase = s * 32 + ((l >> 4) << 3);
        int nn = (T << 4) + (l & 15);
        short8 t;
        #pragma unroll
        for (int j = 0; j < 8; ++j)
            t[j] = (short)f2bf(src[(kbase + j) * 256 + nn]);
        *(short8*)(dst + rest * 8) = t;
        return;
    }

    const int b = blk - 64;
    peL[tid] = patient_emb[b * 256 + tid];
    __syncthreads();
    float x = bp[tid];
    for (int d = 0; d < 256; ++d) x = fmaf(peL[d], Wp[d * 256 + tid], x);
    float s1 = x, s2 = x * x;
    #pragma unroll
    for (int off = 32; off; off >>= 1) {
        s1 += __shfl_xor(s1, off);
        s2 += __shfl_xor(s2, off);
    }
    int w = tid >> 6;
    if ((tid & 63) == 0) { redw[w] = s1; redw[4 + w] = s2; }
    __syncthreads();
    if (tid == 0) {
        float S1 = redw[0] + redw[1] + redw[2] + redw[3];
        float S2 = redw[4] + redw[5] + redw[6] + redw[7];
        float mean = S1 * (1.f / 256.f);
        float var  = S2 * (1.f / 256.f) - mean * mean;
        stat[0] = mean; stat[1] = rsqrtf(var + 1e-5f);
    }
    __syncthreads();
    xb[tid] = (x - stat[0]) * stat[1] * gp[tid] + betap[tid];
    __syncthreads();
    float y = 0.f;
    for (int d = 0; d < 256; ++d) y = fmaf(xb[d], W1[d * 256 + tid], y);
    EpT[tid * 16 + b] = exp2_fast(C2F * y);   // [h][b]
}

// ---------------------------------------------------------------------------
// mega: one wave per 16 v-rows; no __syncthreads anywhere.
// MFMA 16x16x32_bf16: A lane: A[m=lane&15][k=(lane>>4)*8+j]; C/D:
// D[(lane>>4)*4+r][lane&15].
// ---------------------------------------------------------------------------
__global__ __launch_bounds__(64) void mega_kernel(
    const float* __restrict__ atc4, const float* __restrict__ ba,
    const float* __restrict__ ga, const float* __restrict__ betaa,
    const float* __restrict__ b1, const float* __restrict__ W2,
    const ushort_t* __restrict__ pWa, const ushort_t* __restrict__ pW1b,
    const float* __restrict__ EpT, float* __restrict__ scores,
    float* __restrict__ s1g, float* __restrict__ s2g)
{
    __shared__ ushort_t Atile[16 * 264];   // 16 rows x (256+8 pad) bf16
    __shared__ float EpL[256 * 20];        // [h][b] padded: stride 20 floats

    const int lane = threadIdx.x;
    const int q = lane >> 4, n = lane & 15;
    const int v0 = blockIdx.x * 16;

    // stage EpT (16KB) -> padded LDS; wave-local, no barrier needed
    #pragma unroll
    for (int i = 0; i < 16; ++i) {
        int idx = i * 64 + lane;                       // float4 id (1024 total)
        float4 val = ((const float4*)EpT)[idx];
        *(float4*)(&EpL[(idx >> 2) * 20 + (idx & 3) * 4]) = val;
    }

    // A fragments straight from global into registers (frag layout)
    short8 af[8];
    #pragma unroll
    for (int s = 0; s < 8; ++s) {
        const float* src = atc4 + (v0 + n) * 256 + s * 32 + q * 8;
        float4 f0 = *(const float4*)(src);
        float4 f1 = *(const float4*)(src + 4);
        short8 t;
        t[0] = (short)f2bf(f0.x); t[1] = (short)f2bf(f0.y);
        t[2] = (short)f2bf(f0.z); t[3] = (short)f2bf(f0.w);
        t[4] = (short)f2bf(f1.x); t[5] = (short)f2bf(f1.y);
        t[6] = (short)f2bf(f1.z); t[7] = (short)f2bf(f1.w);
        af[s] = t;
    }

    // ---- GEMM1: acc[ni] = atc4_tile @ Wa  (cols ni*16+n) ----
    floatx4 acc[16];
    #pragma unroll
    for (int ni = 0; ni < 16; ++ni) acc[ni] = (floatx4){0.f, 0.f, 0.f, 0.f};
    #pragma unroll
    for (int s = 0; s < 8; ++s) {
        #pragma unroll
        for (int ni = 0; ni < 16; ++ni) {
            short8 bf = *(const short8*)(pWa + ((s * 16 + ni) * 64 + lane) * 8);
            acc[ni] = __builtin_amdgcn_mfma_f32_16x16x32_bf16(af[s], bf, acc[ni], 0, 0, 0);
        }
    }

    // ---- bias + row-LN fully in-register (rows q*4+r, reduce over 16 n-lanes)
    float s1v[4] = {0, 0, 0, 0}, s2v[4] = {0, 0, 0, 0};
    #pragma unroll
    for (int ni = 0; ni < 16; ++ni) {
        float bav = ba[ni * 16 + n];
        #pragma unroll
        for (int r = 0; r < 4; ++r) {
            float x = acc[ni][r] + bav;
            acc[ni][r] = x;
            s1v[r] += x; s2v[r] += x * x;
        }
    }
    #pragma unroll
    for (int off = 1; off < 16; off <<= 1)
        #pragma unroll
        for (int r = 0; r < 4; ++r) {
            s1v[r] += __shfl_xor(s1v[r], off);
            s2v[r] += __shfl_xor(s2v[r], off);
        }
    float mean[4], rstd[4];
    #pragma unroll
    for (int r = 0; r < 4; ++r) {
        mean[r] = s1v[r] * (1.f / 256.f);
        float var = s2v[r] * (1.f / 256.f) - mean[r] * mean[r];
        rstd[r] = rsqrtf(var + 1e-5f);
    }
    // C/D layout -> A layout via wave-private LDS tile
    #pragma unroll
    for (int ni = 0; ni < 16; ++ni) {
        float gav = ga[ni * 16 + n], bev = betaa[ni * 16 + n];
        #pragma unroll
        for (int r = 0; r < 4; ++r) {
            float xv = (acc[ni][r] - mean[r]) * rstd[r] * gav + bev;
            Atile[(q * 4 + r) * 264 + ni * 16 + n] = f2bf(xv);
        }
    }

    // ---- GEMM2: acc2[ni] = LN(a) @ W1[D:] ----
    floatx4 acc2[16];
    #pragma unroll
    for (int ni = 0; ni < 16; ++ni) acc2[ni] = (floatx4){0.f, 0.f, 0.f, 0.f};
    #pragma unroll
    for (int s = 0; s < 8; ++s) {
        short8 af2 = *(const short8*)(&Atile[n * 264 + s * 32 + q * 8]);
        #pragma unroll
        for (int ni = 0; ni < 16; ++ni) {
            short8 bf = *(const short8*)(pW1b + ((s * 16 + ni) * 64 + lane) * 8);
            acc2[ni] = __builtin_amdgcn_mfma_f32_16x16x32_bf16(af2, bf, acc2[ni], 0, 0, 0);
        }
    }

    // ---- fused tanh contraction: accs[b][r] = sum_h W2[h]/(1+Ep[b][h]*Ea[v][h])
    float accs[16][4];
    #pragma unroll
    for (int b = 0; b < 16; ++b)
        #pragma unroll
        for (int r = 0; r < 4; ++r) accs[b][r] = 0.f;
    #pragma unroll
    for (int ni = 0; ni < 16; ++ni) {
        float b1v = C2F * b1[ni * 16 + n];
        float w2v = W2[ni * 16 + n];
        float Ea[4];
        #pragma unroll
        for (int r = 0; r < 4; ++r)
            Ea[r] = exp2_fast(fmaf(C2F, acc2[ni][r], b1v));
        #pragma unroll
        for (int bq = 0; bq < 4; ++bq) {
            float4 ep = *(const float4*)(&EpL[(ni * 16 + n) * 20 + bq * 4]);
            float epv[4] = {ep.x, ep.y, ep.z, ep.w};
            #pragma unroll
            for (int bb = 0; bb < 4; ++bb)
                #pragma unroll
                for (int r = 0; r < 4; ++r)
                    accs[bq * 4 + bb][r] += w2v * rcp_fast(fmaf(epv[bb], Ea[r], 1.f));
        }
    }

    // ---- butterfly reduce-scatter over the 16 n-lanes: lane n ends with b=n
    float a8[8][4], a4[4][4], a2v[2][4], afin[4];
    {
        bool hb = (n & 1) != 0;
        #pragma unroll
        for (int p = 0; p < 8; ++p)
            #pragma unroll
            for (int r = 0; r < 4; ++r) {
                float keep = hb ? accs[2 * p + 1][r] : accs[2 * p][r];
                float send = hb ? accs[2 * p][r] : accs[2 * p + 1][r];
                a8[p][r] = keep + __shfl_xor(send, 1);
            }
        hb = (n & 2) != 0;
        #pragma unroll
        for (int p = 0; p < 4; ++p)
            #pragma unroll
            for (int r = 0; r < 4; ++r) {
                float keep = hb ? a8[2 * p + 1][r] : a8[2 * p][r];
                float send = hb ? a8[2 * p][r] : a8[2 * p + 1][r];
                a4[p][r] = keep + __shfl_xor(send, 2);
            }
        hb = (n & 4) != 0;
        #pragma unroll
        for (int p = 0; p < 2; ++p)
            #pragma unroll
            for (int r = 0; r < 4; ++r) {
                float keep = hb ? a4[2 * p + 1][r] : a4[2 * p][r];
                float send = hb ? a4[2 * p][r] : a4[2 * p + 1][r];
                a2v[p][r] = keep + __shfl_xor(send, 4);
            }
        hb = (n & 8) != 0;
        #pragma unroll
        for (int r = 0; r < 4; ++r) {
            float keep = hb ? a2v[1][r] : a2v[0][r];
            float send = hb ? a2v[0][r] : a2v[1][r];
            afin[r] = keep + __shfl_xor(send, 8);
        }
    }

    // lane (q,n): scores[b=n][v0+q*4 .. +3], aligned float4
    *(float4*)(scores + n * V_N + v0 + q * 4) =
        make_float4(afin[0], afin[1], afin[2], afin[3]);

    // per-block LN partials (sum over this block's 16 v) per b
    float ls1 = afin[0] + afin[1] + afin[2] + afin[3];
    float ls2 = afin[0] * afin[0] + afin[1] * afin[1] +
                afin[2] * afin[2] + afin[3] * afin[3];
    ls1 += __shfl_xor(ls1, 16); ls1 += __shfl_xor(ls1, 32);
    ls2 += __shfl_xor(ls2, 16); ls2 += __shfl_xor(ls2, 32);
    if (lane < 16) {
        s1g[n * NBLK + blockIdx.x] = ls1;
        s2g[n * NBLK + blockIdx.x] = ls2;
    }
}

// ---------------------------------------------------------------------------
// final: grid (10 chunks, 16 b). Redundant cheap stats reduce per block, then
// elementwise: out = -2*(S-mean)*rsqrt(4*var+eps)*g_pred + b_pred.
// ---------------------------------------------------------------------------
__global__ __launch_bounds__(256) void final_kernel(
    const float* __restrict__ scores, const float* __restrict__ s1g,
    const float* __restrict__ s2g, const float* __restrict__ g_pred,
    const float* __restrict__ b_pred, float* __restrict__ out)
{
    const int cx = blockIdx.x, b = blockIdx.y, tid = threadIdx.x;
    __shared__ float redL[8];
    float ls1 = 0.f, ls2 = 0.f;
    for (int i = tid; i < NBLK; i += 256) {
        ls1 += s1g[b * NBLK + i];
        ls2 += s2g[b * NBLK + i];
    }
    #pragma unroll
    for (int off = 32; off; off >>= 1) {
        ls1 += __shfl_xor(ls1, off);
        ls2 += __shfl_xor(ls2, off);
    }
    int w = tid >> 6;
    if ((tid & 63) == 0) { redL[w] = ls1; redL[4 + w] = ls2; }
    __syncthreads();
    float S1 = redL[0] + redL[1] + redL[2] + redL[3];
    float S2 = redL[4] + redL[5] + redL[6] + redL[7];
    float mean = S1 * (1.f / 20000.f);
    float var  = S2 * (1.f / 20000.f) - mean * mean;
    float k = -2.f * rsqrtf(4.f * var + 1e-5f);
    #pragma unroll
    for (int i = 0; i < 8; ++i) {
        int off = i * 256 + tid;
        if (off < 2000) {
            int v = cx * 2000 + off;
            float S = scores[b * V_N + v];
            out[b * V_N + v] = (S - mean) * k * g_pred[v] + b_pred[v];
        }
    }
}

extern "C" void kernel_launch(void* const* d_in, const int* in_sizes, int n_in,
                              void* d_out, int out_size, void* d_ws, size_t ws_size,
                              hipStream_t stream)
{
    const float* patient_emb = (const float*)d_in[0];
    const float* atc4        = (const float*)d_in[1];
    const float* Wp     = (const float*)d_in[2];
    const float* bp     = (const float*)d_in[3];
    const float* gp     = (const float*)d_in[4];
    const float* betap  = (const float*)d_in[5];
    const float* Wa     = (const float*)d_in[6];
    const float* ba     = (const float*)d_in[7];
    const float* ga     = (const float*)d_in[8];
    const float* betaa  = (const float*)d_in[9];
    const float* W1     = (const float*)d_in[10];
    const float* b1     = (const float*)d_in[11];
    const float* W2     = (const float*)d_in[12];
    // d_in[13] = b2: constant, cancels under the final LN
    const float* g_pred = (const float*)d_in[14];
    const float* b_pred = (const float*)d_in[15];

    char* ws = (char*)d_ws;
    float*    EpT    = (float*)(ws);                 //  16384 B
    ushort_t* pWa    = (ushort_t*)(ws + 16384);      // 131072 B
    ushort_t* pW1b   = (ushort_t*)(ws + 147456);     // 131072 B
    float*    scores = (float*)(ws + 278528);        // 1280000 B
    float*    s1g    = (float*)(ws + 1558528);       //  80000 B
    float*    s2g    = (float*)(ws + 1638528);       //  80000 B
    float*    out    = (float*)d_out;

    prep_kernel<<<80, 256, 0, stream>>>(patient_emb, Wp, bp, gp, betap,
                                        Wa, W1, pWa, pW1b, EpT);
    mega_kernel<<<NBLK, 64, 0, stream>>>(atc4, ba, ga, betaa, b1, W2,
                                         pWa, pW1b, EpT, scores, s1g, s2g);
    final_kernel<<<dim3(10, 16), 256, 0, stream>>>(scores, s1g, s2g,
                                                   g_pred, b_pred, out);
}

// Round 3
// 155.070 us; speedup vs baseline: 2.1776x; 2.1776x over previous
//
#include <hip/hip_runtime.h>

// B=16, V=20000, D=H=256. Output fp32 [16][20000].
// prep:  repack Wa/W1[D:] to MFMA B-frag bf16; patient path -> EpT[h][b]=exp2(C*ph)
// mega:  625 blocks x 4 waves, 32 v-rows/block, h split across waves (64 each).
//        GEMM1 (bf16 MFMA) + cross-wave row-LN -> frag-order LDS -> GEMM2 ->
//        Ea=exp2 -> fused tanh contraction (2 passes of 8 batch rows) -> scores.
// final: stats reduce + LN over V.
// tanh(z)=1-2/(1+e^{2z}); constants cancel in final LN (shift-invariant):
// out = -2*(S-mean_S)*rsqrt(4*var_S+eps)*g_pred + b_pred, S = sum_h W2/(1+Ep*Ea).

typedef unsigned short ushort_t;
typedef __attribute__((ext_vector_type(8))) short short8;
typedef __attribute__((ext_vector_type(4))) float floatx4;

#define C2F 2.8853900817779268f  // 2*log2(e)
#define V_N 20000
#define NBLK 625                 // V_N / 32

__device__ __forceinline__ ushort_t f2bf(float f) {
    unsigned int u = __builtin_bit_cast(unsigned int, f);
    u += 0x7FFFu + ((u >> 16) & 1u);   // RNE
    return (ushort_t)(u >> 16);
}
__device__ __forceinline__ float exp2_fast(float x) { return __builtin_amdgcn_exp2f(x); }
__device__ __forceinline__ float rcp_fast(float x)  { return __builtin_amdgcn_rcpf(x); }

// ---------------------------------------------------------------------------
// prep: blocks 0..15 repack Wa / W1[D:] into B-frag order (validated R1/R2):
//   elem ((s*16+T)*64+l)*8+j = src[(s*32+(l>>4)*8+j)*256 + T*16+(l&15)]
// blocks 16..31: patient path, one block per b -> EpT[h*16+b]
// ---------------------------------------------------------------------------
__global__ __launch_bounds__(1024) void prep_kernel(
    const float* __restrict__ patient_emb, const float* __restrict__ Wp,
    const float* __restrict__ bp, const float* __restrict__ gp,
    const float* __restrict__ betap, const float* __restrict__ Wa,
    const float* __restrict__ W1, ushort_t* __restrict__ pWa,
    ushort_t* __restrict__ pW1b, float* __restrict__ EpT)
{
    const int blk = blockIdx.x;
    const int tid = threadIdx.x;
    __shared__ float peL[256];
    __shared__ float pL[256];
    __shared__ float part[4][256];
    __shared__ float red[8];

    if (blk < 16) {
        int slot = blk * 1024 + tid;        // 16384 slots = 2 matrices * 8192
        int matrix = slot >> 13;
        int rest = slot & 8191;
        int s = rest >> 10, T = (rest >> 6) & 15, l = rest & 63;
        const float* src = matrix ? (W1 + 256 * 256) : Wa;
        ushort_t* dst = matrix ? pW1b : pWa;
        int kbase = s * 32 + ((l >> 4) << 3);
        int nn = (T << 4) + (l & 15);
        short8 t;
        #pragma unroll
        for (int j = 0; j < 8; ++j)
            t[j] = (short)f2bf(src[(kbase + j) * 256 + nn]);
        *(short8*)(dst + rest * 8) = t;
        return;
    }

    const int b = blk - 16;
    const int j = tid & 255, pq = tid >> 8;   // 4-way K split
    if (tid < 256) peL[tid] = patient_emb[b * 256 + tid];
    __syncthreads();
    float a0 = 0.f;
    #pragma unroll 8
    for (int dd = 0; dd < 64; ++dd) {
        int d = pq * 64 + dd;
        a0 += peL[d] * Wp[d * 256 + j];
    }
    part[pq][j] = a0;
    __syncthreads();
    float x = 0.f;
    if (tid < 256) {
        x = part[0][j] + part[1][j] + part[2][j] + part[3][j] + bp[j];
        float s1 = x, s2 = x * x;
        #pragma unroll
        for (int off = 32; off; off >>= 1) {
            s1 += __shfl_xor(s1, off);
            s2 += __shfl_xor(s2, off);
        }
        int wv = tid >> 6;
        if ((tid & 63) == 0) { red[wv * 2] = s1; red[wv * 2 + 1] = s2; }
    }
    __syncthreads();
    if (tid < 256) {
        float s1 = red[0] + red[2] + red[4] + red[6];
        float s2 = red[1] + red[3] + red[5] + red[7];
        float mean = s1 * (1.f / 256.f);
        float var  = s2 * (1.f / 256.f) - mean * mean;
        float rstd = rsqrtf(var + 1e-5f);
        pL[tid] = (x - mean) * rstd * gp[tid] + betap[tid];
    }
    __syncthreads();
    float a2 = 0.f;
    #pragma unroll 8
    for (int dd = 0; dd < 64; ++dd) {
        int d = pq * 64 + dd;
        a2 += pL[d] * W1[d * 256 + j];   // W1[:D]
    }
    part[pq][j] = a2;
    __syncthreads();
    if (tid < 256)
        EpT[tid * 16 + b] = exp2_fast(
            C2F * (part[0][tid] + part[1][tid] + part[2][tid] + part[3][tid]));
}

// ---------------------------------------------------------------------------
// mega: 256 threads (4 waves), 32 v-rows. Wave w owns h/d cols [64w,64w+64).
// MFMA 16x16x32_bf16: A lane: A[m=lane&15][k=(lane>>4)*8+j]; C/D:
// D[(lane>>4)*4+r][lane&15]. A tiles stored in LDS in frag order:
//   short8 slot (mi*8+s)*64+lane  <->  A[row=mi*16+(lane&15)][k=s*32+(lane>>4)*8+j]
// ---------------------------------------------------------------------------
__global__ __launch_bounds__(256) void mega_kernel(
    const float* __restrict__ atc4, const float* __restrict__ ba,
    const float* __restrict__ ga, const float* __restrict__ betaa,
    const float* __restrict__ b1, const float* __restrict__ W2,
    const ushort_t* __restrict__ pWa, const ushort_t* __restrict__ pW1b,
    const float* __restrict__ EpT, float* __restrict__ scores,
    float* __restrict__ s1g, float* __restrict__ s2g)
{
    __shared__ ushort_t AtileF[8192];      // 16 KB, frag order (2 mi x 8 s x 64 x 8)
    __shared__ float EpL[256 * 17];        // [h*17 + b], pad 17 -> conflict-free
    __shared__ float statsP[4][32][2];
    __shared__ float statsF[32][2];
    __shared__ float redbuf[2][1056];      // [pass][(w*8+b)*33 + v]

    const int tid = threadIdx.x;
    const int w = tid >> 6, lane = tid & 63;
    const int q = lane >> 4, n = lane & 15;
    const int v0 = blockIdx.x * 32;

    // ---- stage EpL (shared by all 4 waves) ----
    #pragma unroll
    for (int i = 0; i < 16; ++i) {
        int idx = i * 256 + tid;
        EpL[(idx >> 4) * 17 + (idx & 15)] = EpT[idx];
    }
    // ---- stage A tile straight into frag order ----
    {
        const int r_ = tid >> 3, s_ = tid & 7;
        const int mi_ = r_ >> 4, n_ = r_ & 15;
        const float* srcp = atc4 + (v0 + r_) * 256 + s_ * 32;
        #pragma unroll
        for (int j = 0; j < 8; ++j) {
            float4 f = ((const float4*)srcp)[j];
            ushort4 usv = make_ushort4(f2bf(f.x), f2bf(f.y), f2bf(f.z), f2bf(f.w));
            int addr = ((mi_ * 8 + s_) * 64 + (j >> 1) * 16 + n_) * 8 + (j & 1) * 4;
            *(ushort4*)(AtileF + addr) = usv;
        }
    }
    __syncthreads();

    // ---- GEMM1: cols w*64 + ni*16 + n ----
    floatx4 acc[2][4];
    #pragma unroll
    for (int mi = 0; mi < 2; ++mi)
        #pragma unroll
        for (int ni = 0; ni < 4; ++ni) acc[mi][ni] = (floatx4){0.f, 0.f, 0.f, 0.f};
    #pragma unroll
    for (int s = 0; s < 8; ++s) {
        short8 a0 = ((const short8*)AtileF)[s * 64 + lane];
        short8 a1 = ((const short8*)AtileF)[(8 + s) * 64 + lane];
        #pragma unroll
        for (int ni = 0; ni < 4; ++ni) {
            short8 bfv = *(const short8*)(pWa + ((s * 16 + w * 4 + ni) * 64 + lane) * 8);
            acc[0][ni] = __builtin_amdgcn_mfma_f32_16x16x32_bf16(a0, bfv, acc[0][ni], 0, 0, 0);
            acc[1][ni] = __builtin_amdgcn_mfma_f32_16x16x32_bf16(a1, bfv, acc[1][ni], 0, 0, 0);
        }
    }

    // ---- per-col params ----
    float bac[4], gac[4], bec[4], b1c[4], w2c[4];
    #pragma unroll
    for (int ni = 0; ni < 4; ++ni) {
        int col = w * 64 + ni * 16 + n;
        bac[ni] = ba[col]; gac[ni] = ga[col]; bec[ni] = betaa[col];
        b1c[ni] = C2F * b1[col]; w2c[ni] = W2[col];
    }

    // ---- bias + partial LN stats (this wave covers 64 of 256 cols) ----
    float s1v[8] = {0, 0, 0, 0, 0, 0, 0, 0}, s2v[8] = {0, 0, 0, 0, 0, 0, 0, 0};
    #pragma unroll
    for (int mi = 0; mi < 2; ++mi)
        #pragma unroll
        for (int ni = 0; ni < 4; ++ni)
            #pragma unroll
            for (int r = 0; r < 4; ++r) {
                float x = acc[mi][ni][r] + bac[ni];
                acc[mi][ni][r] = x;
                s1v[mi * 4 + r] += x;
                s2v[mi * 4 + r] += x * x;
            }
    #pragma unroll
    for (int off = 1; off < 16; off <<= 1)
        #pragma unroll
        for (int k = 0; k < 8; ++k) {
            s1v[k] += __shfl_xor(s1v[k], off);
            s2v[k] += __shfl_xor(s2v[k], off);
        }
    if (n == 0) {
        #pragma unroll
        for (int mi = 0; mi < 2; ++mi)
            #pragma unroll
            for (int r = 0; r < 4; ++r) {
                int row = mi * 16 + q * 4 + r;
                statsP[w][row][0] = s1v[mi * 4 + r];
                statsP[w][row][1] = s2v[mi * 4 + r];
            }
    }
    __syncthreads();
    if (tid < 32) {
        float m1 = statsP[0][tid][0] + statsP[1][tid][0] + statsP[2][tid][0] + statsP[3][tid][0];
        float m2 = statsP[0][tid][1] + statsP[1][tid][1] + statsP[2][tid][1] + statsP[3][tid][1];
        float mean = m1 * (1.f / 256.f);
        float var  = m2 * (1.f / 256.f) - mean * mean;
        statsF[tid][0] = mean;
        statsF[tid][1] = rsqrtf(var + 1e-5f);
    }
    __syncthreads();

    // ---- LN apply; scatter bf16 result back into AtileF in frag order ----
    // value (row = mi*16+q*4+r, d = w*64+ni*16+n):
    //   s2 = w*2+(ni>>1); q2 = (ni&1)*2+(n>>3); j2 = n&7; nrow = q*4+r
    #pragma unroll
    for (int mi = 0; mi < 2; ++mi)
        #pragma unroll
        for (int r = 0; r < 4; ++r) {
            int row = mi * 16 + q * 4 + r;
            float mean = statsF[row][0], rstd = statsF[row][1];
            #pragma unroll
            for (int ni = 0; ni < 4; ++ni) {
                float xv = (acc[mi][ni][r] - mean) * rstd * gac[ni] + bec[ni];
                int addr = ((mi * 8 + (w * 2 + (ni >> 1))) * 64 +
                            ((ni & 1) * 2 + (n >> 3)) * 16 + (q * 4 + r)) * 8 + (n & 7);
                AtileF[addr] = f2bf(xv);
            }
        }
    __syncthreads();

    // ---- GEMM2 ----
    floatx4 acc2[2][4];
    #pragma unroll
    for (int mi = 0; mi < 2; ++mi)
        #pragma unroll
        for (int ni = 0; ni < 4; ++ni) acc2[mi][ni] = (floatx4){0.f, 0.f, 0.f, 0.f};
    #pragma unroll
    for (int s = 0; s < 8; ++s) {
        short8 a0 = ((const short8*)AtileF)[s * 64 + lane];
        short8 a1 = ((const short8*)AtileF)[(8 + s) * 64 + lane];
        #pragma unroll
        for (int ni = 0; ni < 4; ++ni) {
            short8 bfv = *(const short8*)(pW1b + ((s * 16 + w * 4 + ni) * 64 + lane) * 8);
            acc2[0][ni] = __builtin_amdgcn_mfma_f32_16x16x32_bf16(a0, bfv, acc2[0][ni], 0, 0, 0);
            acc2[1][ni] = __builtin_amdgcn_mfma_f32_16x16x32_bf16(a1, bfv, acc2[1][ni], 0, 0, 0);
        }
    }

    // ---- Ea = exp2(C*(ah + b1)) ----
    float Ea[2][4][4];
    #pragma unroll
    for (int mi = 0; mi < 2; ++mi)
        #pragma unroll
        for (int ni = 0; ni < 4; ++ni)
            #pragma unroll
            for (int r = 0; r < 4; ++r)
                Ea[mi][ni][r] = exp2_fast(fmaf(C2F, acc2[mi][ni][r], b1c[ni]));

    // ---- contraction, two passes of 8 batch rows ----
    #pragma unroll
    for (int p = 0; p < 2; ++p) {
        float accs[8][8];
        #pragma unroll
        for (int bb = 0; bb < 8; ++bb)
            #pragma unroll
            for (int v = 0; v < 8; ++v) accs[bb][v] = 0.f;
        #pragma unroll
        for (int ni = 0; ni < 4; ++ni) {
            int base = (w * 64 + ni * 16 + n) * 17 + p * 8;
            float ep[8];
            #pragma unroll
            for (int bb = 0; bb < 8; ++bb) ep[bb] = EpL[base + bb];
            #pragma unroll
            for (int bb = 0; bb < 8; ++bb)
                #pragma unroll
                for (int mi = 0; mi < 2; ++mi)
                    #pragma unroll
                    for (int r = 0; r < 4; ++r)
                        accs[bb][mi * 4 + r] +=
                            w2c[ni] * rcp_fast(fmaf(ep[bb], Ea[mi][ni][r], 1.f));
        }
        // reduce-scatter over 16 n-lanes: lane ends with b = n&7 (full h-group sum)
        float t4[4][8], t2v[2][8], t1[8], afin[8];
        {
            int hb = n & 1;
            #pragma unroll
            for (int p2 = 0; p2 < 4; ++p2)
                #pragma unroll
                for (int v = 0; v < 8; ++v) {
                    float keep = hb ? accs[2 * p2 + 1][v] : accs[2 * p2][v];
                    float send = hb ? accs[2 * p2][v] : accs[2 * p2 + 1][v];
                    t4[p2][v] = keep + __shfl_xor(send, 1);
                }
            hb = (n >> 1) & 1;
            #pragma unroll
            for (int p2 = 0; p2 < 2; ++p2)
                #pragma unroll
                for (int v = 0; v < 8; ++v) {
                    float keep = hb ? t4[2 * p2 + 1][v] : t4[2 * p2][v];
                    float send = hb ? t4[2 * p2][v] : t4[2 * p2 + 1][v];
                    t2v[p2][v] = keep + __shfl_xor(send, 2);
                }
            hb = (n >> 2) & 1;
            #pragma unroll
            for (int v = 0; v < 8; ++v) {
                float keep = hb ? t2v[1][v] : t2v[0][v];
                float send = hb ? t2v[0][v] : t2v[1][v];
                t1[v] = keep + __shfl_xor(send, 4);
            }
            #pragma unroll
            for (int v = 0; v < 8; ++v)
                afin[v] = t1[v] + __shfl_xor(t1[v], 8);
        }
        if (n < 8) {
            #pragma unroll
            for (int mi = 0; mi < 2; ++mi)
                #pragma unroll
                for (int r = 0; r < 4; ++r)
                    redbuf[p][(w * 8 + n) * 33 + mi * 16 + q * 4 + r] = afin[mi * 4 + r];
        }
        __syncthreads();
        {
            int bb = tid >> 5, v = tid & 31;
            float S = redbuf[p][bb * 33 + v] + redbuf[p][(8 + bb) * 33 + v] +
                      redbuf[p][(16 + bb) * 33 + v] + redbuf[p][(24 + bb) * 33 + v];
            int bg = p * 8 + bb;
            scores[bg * V_N + v0 + v] = S;
            float ls1 = S, ls2 = S * S;
            #pragma unroll
            for (int off = 1; off < 32; off <<= 1) {
                ls1 += __shfl_xor(ls1, off);
                ls2 += __shfl_xor(ls2, off);
            }
            if ((tid & 31) == 0) {
                s1g[bg * NBLK + blockIdx.x] = ls1;
                s2g[bg * NBLK + blockIdx.x] = ls2;
            }
        }
    }
}

// ---------------------------------------------------------------------------
// final: grid (10 chunks, 16 b). Redundant cheap stats reduce per block, then
// out = -2*(S-mean)*rsqrt(4*var+eps)*g_pred + b_pred.
// ---------------------------------------------------------------------------
__global__ __launch_bounds__(256) void final_kernel(
    const float* __restrict__ scores, const float* __restrict__ s1g,
    const float* __restrict__ s2g, const float* __restrict__ g_pred,
    const float* __restrict__ b_pred, float* __restrict__ out)
{
    const int cx = blockIdx.x, b = blockIdx.y, tid = threadIdx.x;
    __shared__ float redL[8];
    float ls1 = 0.f, ls2 = 0.f;
    for (int i = tid; i < NBLK; i += 256) {
        ls1 += s1g[b * NBLK + i];
        ls2 += s2g[b * NBLK + i];
    }
    #pragma unroll
    for (int off = 32; off; off >>= 1) {
        ls1 += __shfl_xor(ls1, off);
        ls2 += __shfl_xor(ls2, off);
    }
    int w = tid >> 6;
    if ((tid & 63) == 0) { redL[w] = ls1; redL[4 + w] = ls2; }
    __syncthreads();
    float S1 = redL[0] + redL[1] + redL[2] + redL[3];
    float S2 = redL[4] + redL[5] + redL[6] + redL[7];
    float mean = S1 * (1.f / 20000.f);
    float var  = S2 * (1.f / 20000.f) - mean * mean;
    float k = -2.f * rsqrtf(4.f * var + 1e-5f);
    #pragma unroll
    for (int i = 0; i < 8; ++i) {
        int off = i * 256 + tid;
        if (off < 2000) {
            int v = cx * 2000 + off;
            float S = scores[b * V_N + v];
            out[b * V_N + v] = (S - mean) * k * g_pred[v] + b_pred[v];
        }
    }
}

extern "C" void kernel_launch(void* const* d_in, const int* in_sizes, int n_in,
                              void* d_out, int out_size, void* d_ws, size_t ws_size,
                              hipStream_t stream)
{
    const float* patient_emb = (const float*)d_in[0];
    const float* atc4        = (const float*)d_in[1];
    const float* Wp     = (const float*)d_in[2];
    const float* bp     = (const float*)d_in[3];
    const float* gp     = (const float*)d_in[4];
    const float* betap  = (const float*)d_in[5];
    const float* Wa     = (const float*)d_in[6];
    const float* ba     = (const float*)d_in[7];
    const float* ga     = (const float*)d_in[8];
    const float* betaa  = (const float*)d_in[9];
    const float* W1     = (const float*)d_in[10];
    const float* b1     = (const float*)d_in[11];
    const float* W2     = (const float*)d_in[12];
    // d_in[13] = b2: constant, cancels under the final LN
    const float* g_pred = (const float*)d_in[14];
    const float* b_pred = (const float*)d_in[15];

    char* ws = (char*)d_ws;
    float*    EpT    = (float*)(ws);                 //  16384 B
    ushort_t* pWa    = (ushort_t*)(ws + 16384);      // 131072 B
    ushort_t* pW1b   = (ushort_t*)(ws + 147456);     // 131072 B
    float*    scores = (float*)(ws + 278528);        // 1280000 B
    float*    s1g    = (float*)(ws + 1558528);       //  40000 B
    float*    s2g    = (float*)(ws + 1598528);       //  40000 B
    float*    out    = (float*)d_out;

    prep_kernel<<<32, 1024, 0, stream>>>(patient_emb, Wp, bp, gp, betap,
                                         Wa, W1, pWa, pW1b, EpT);
    mega_kernel<<<NBLK, 256, 0, stream>>>(atc4, ba, ga, betaa, b1, W2,
                                          pWa, pW1b, EpT, scores, s1g, s2g);
    final_kernel<<<dim3(10, 16), 256, 0, stream>>>(scores, s1g, s2g,
                                                   g_pred, b_pred, out);
}